// Round 3
// baseline (1012.356 us; speedup 1.0000x reference)
//
#include <hip/hip_runtime.h>
#include <cstdint>
#include <cstddef>

#define HEADS  4
#define HIDC   128
#define CATF   512
#define IN_F   256
#define OUT_F  256

typedef _Float16 f16x8 __attribute__((ext_vector_type(8)));
typedef _Float16 f16x4 __attribute__((ext_vector_type(4)));
typedef float f32x4  __attribute__((ext_vector_type(4)));

__device__ __forceinline__ void async16(const void* g, void* l) {
    __builtin_amdgcn_global_load_lds((const __attribute__((address_space(1))) void*)g,
                                     (__attribute__((address_space(3))) void*)l, 16, 0, 0);
}

// ---------------- CSR build ----------------
__global__ void init_counts(int* cnt, int N) {
    int i = blockIdx.x * blockDim.x + threadIdx.x;
    if (i < N) cnt[i] = 1;  // self loop
}

__global__ void count_dst(const int* __restrict__ dst, int E, int* cnt) {
    int i = blockIdx.x * blockDim.x + threadIdx.x;
    if (i < E) atomicAdd(&cnt[dst[i]], 1);
}

__global__ void scan_partial(const int* __restrict__ cnt, int* excl, int* bsum, int N) {
    __shared__ int tmp[256];
    int i = blockIdx.x * 256 + threadIdx.x;
    int v = (i < N) ? cnt[i] : 0;
    tmp[threadIdx.x] = v;
    __syncthreads();
    for (int off = 1; off < 256; off <<= 1) {
        int t = ((int)threadIdx.x >= off) ? tmp[threadIdx.x - off] : 0;
        __syncthreads();
        tmp[threadIdx.x] += t;
        __syncthreads();
    }
    if (i < N) excl[i] = tmp[threadIdx.x] - v;
    if (threadIdx.x == 255) bsum[blockIdx.x] = tmp[255];
}

__global__ void scan_bsums(int* bsum, int nb) {   // single block, nb <= 256
    __shared__ int tmp[256];
    int v = ((int)threadIdx.x < nb) ? bsum[threadIdx.x] : 0;
    tmp[threadIdx.x] = v;
    __syncthreads();
    for (int off = 1; off < 256; off <<= 1) {
        int t = ((int)threadIdx.x >= off) ? tmp[threadIdx.x - off] : 0;
        __syncthreads();
        tmp[threadIdx.x] += t;
        __syncthreads();
    }
    if ((int)threadIdx.x < nb) bsum[threadIdx.x] = tmp[threadIdx.x] - v;
}

__global__ void add_carry(int* indptr, int* pos, const int* __restrict__ bsum, int N, int total) {
    int i = blockIdx.x * blockDim.x + threadIdx.x;
    if (i < N) {
        int v = indptr[i] + bsum[i >> 8];
        indptr[i] = v;
        pos[i] = v;
    }
    if (i == 0) indptr[N] = total;
}

__global__ void scatter_edges(const int* __restrict__ src, const int* __restrict__ dst,
                              int E, int N, int* pos, int* esrc) {
    int i = blockIdx.x * blockDim.x + threadIdx.x;
    int total = E + N;
    if (i >= total) return;
    int s, d;
    if (i < E) { s = src[i]; d = dst[i]; }
    else       { s = i - E;  d = s; }
    int p = atomicAdd(&pos[d], 1);
    esrc[p] = s;
}

// ---------------- fp32 -> fp16 ----------------
__global__ void conv_h16(const float* __restrict__ in, _Float16* __restrict__ out, long n4) {
    long i = (long)blockIdx.x * blockDim.x + threadIdx.x;
    if (i >= n4) return;
    float4 v = ((const float4*)in)[i];
    f16x4 o = { (_Float16)v.x, (_Float16)v.y, (_Float16)v.z, (_Float16)v.w };
    ((f16x4*)out)[i] = o;
}

// all weights: W[K,N] fp32 -> Wt_hi/Wt_lo [N,K] fp16 (transposed, hi/lo split)
struct WDesc { const float* W; _Float16* hi; _Float16* lo; int K; int N; int off; };
struct WPack { WDesc d[6]; int total; };
__global__ void conv_w_all(WPack p) {
    int idx = blockIdx.x * blockDim.x + threadIdx.x;
    if (idx >= p.total) return;
    int wi = 0;
    while (wi < 5 && idx >= p.d[wi + 1].off) wi++;
    const WDesc& w = p.d[wi];
    int li = idx - w.off;
    int n = li / w.K, k = li - n * w.K;
    float v = w.W[(size_t)k * w.N + n];
    _Float16 h = (_Float16)v;
    w.hi[(size_t)n * w.K + k] = h;
    if (w.lo) w.lo[(size_t)n * w.K + k] = (_Float16)(v - (float)h);
}

__global__ void zero2(float* a, float* b, int n) {
    int i = blockIdx.x * blockDim.x + threadIdx.x;
    if (i < n) { a[i] = 0.f; b[i] = 0.f; }
}

// ---------------- fp16 MFMA GEMM: C = A @ W^T (+ fused attention coefs) ----------------
// A [M,K] fp16; Bh/Bl [N,K] fp16 (transposed weights). NMF=1: hi only; NMF=2: hi+lo.
// MODE 1: fp32 out; MODE 2: fp16 out.
// ATTN 0: none; 1: al_s[gm*4 + n0/128] = sum_c v*asrc[gn] (col-block == head);
//      2: atomicAdd(&al_s[gm], ...) (single head spanning multiple col-blocks).
#define TM 128
#define TN 128
#define TK 32
template <int MODE, int NMF, int ATTN>
__global__ __launch_bounds__(256) void gemm_bt(
        const _Float16* __restrict__ A,
        const _Float16* __restrict__ Bh, const _Float16* __restrict__ Bl,
        const float* __restrict__ bias,
        float* __restrict__ out_f, _Float16* __restrict__ out_h16,
        const float* __restrict__ asrc, const float* __restrict__ adst,
        float* __restrict__ al_s, float* __restrict__ al_d,
        int M, int N, int K, int act) {
    __shared__ __align__(16) _Float16 sA[TM * TK], sBh[TN * TK];
    __shared__ __align__(16) _Float16 sBl[NMF == 2 ? TN * TK : 16];
    __shared__ float sred[ATTN ? TM * 4 : 4];   // [row][s/d][wn]
    int tid = threadIdx.x;
    int wave = tid >> 6, lane = tid & 63;
    int m0 = blockIdx.y * TM, n0 = blockIdx.x * TN;
    int wm = wave >> 1, wn = wave & 1;           // 2x2 waves, each 64x64
    int srow = lane >> 2;
    int skel = (lane & 3) * 8;
    int fr = lane & 15, quad = lane >> 4;

    f32x4 acc[4][4];
#pragma unroll
    for (int i = 0; i < 4; i++)
#pragma unroll
        for (int j = 0; j < 4; j++) acc[i][j] = (f32x4){0.f, 0.f, 0.f, 0.f};

    for (int k0 = 0; k0 < K; k0 += TK) {
        __syncthreads();
#pragma unroll
        for (int c = 0; c < 2; c++) {
            int chunk = wave * 2 + c;
            int r = chunk * 16 + srow;
            int gmA = m0 + r; if (gmA >= M) gmA = M - 1;
            int gnB = n0 + r;
            size_t aoff = (size_t)gmA * K + k0 + skel;
            size_t boff = (size_t)gnB * K + k0 + skel;
            int ldso = chunk * 512;              // halfs (1 KB chunks)
            async16(A + aoff, &sA[ldso]);
            async16(Bh + boff, &sBh[ldso]);
            if (NMF == 2) async16(Bl + boff, &sBl[ldso]);
        }
        __syncthreads();

        f16x8 fa[4], fbh[4], fbl[4];
#pragma unroll
        for (int i = 0; i < 4; i++) {
            int ra = (wm * 64 + i * 16 + fr) * TK + quad * 8;
            int rb = (wn * 64 + i * 16 + fr) * TK + quad * 8;
            fa[i]  = *(const f16x8*)&sA[ra];
            fbh[i] = *(const f16x8*)&sBh[rb];
            if (NMF == 2) fbl[i] = *(const f16x8*)&sBl[rb];
        }
#pragma unroll
        for (int i = 0; i < 4; i++)
#pragma unroll
            for (int j = 0; j < 4; j++) {
                if (NMF == 2)
                    acc[i][j] = __builtin_amdgcn_mfma_f32_16x16x32_f16(fa[i], fbl[j], acc[i][j], 0, 0, 0);
                acc[i][j] = __builtin_amdgcn_mfma_f32_16x16x32_f16(fa[i], fbh[j], acc[i][j], 0, 0, 0);
            }
    }

    float avs[4], avd[4];
    if (ATTN) {
#pragma unroll
        for (int j = 0; j < 4; j++) {
            int gn = n0 + wn * 64 + j * 16 + fr;
            avs[j] = asrc[gn];
            avd[j] = adst[gn];
        }
        __syncthreads();   // done with sA; sred may alias activity timing
    }

#pragma unroll
    for (int i = 0; i < 4; i++)
#pragma unroll
        for (int r = 0; r < 4; r++) {
            int gm = m0 + wm * 64 + i * 16 + quad * 4 + r;
            if (gm >= M) continue;     // uniform across the 16-lane fr group
            float ps = 0.f, pd = 0.f;
#pragma unroll
            for (int j = 0; j < 4; j++) {
                int gn = n0 + wn * 64 + j * 16 + fr;
                float v = acc[i][j][r];
                if (bias) v += bias[gn];
                if (act == 1) v = fmaxf(v, 0.f);
                size_t o = (size_t)gm * N + gn;
                if (MODE == 1) out_f[o] = v;
                else           out_h16[o] = (_Float16)v;
                if (ATTN) { ps += v * avs[j]; pd += v * avd[j]; }
            }
            if (ATTN) {
#pragma unroll
                for (int off = 1; off < 16; off <<= 1) {
                    ps += __shfl_xor(ps, off);
                    pd += __shfl_xor(pd, off);
                }
                if (fr == 0) {
                    int lrow = wm * 64 + i * 16 + quad * 4 + r;
                    sred[lrow * 4 + 0 * 2 + wn] = ps;
                    sred[lrow * 4 + 1 * 2 + wn] = pd;
                }
            }
        }

    if (ATTN) {
        __syncthreads();
        if (tid < TM) {
            int gm = m0 + tid;
            if (gm < M) {
                float s = sred[tid * 4 + 0] + sred[tid * 4 + 1];
                float d = sred[tid * 4 + 2] + sred[tid * 4 + 3];
                if (ATTN == 1) {
                    int head = n0 >> 7;
                    al_s[gm * HEADS + head] = s;
                    al_d[gm * HEADS + head] = d;
                } else {
                    atomicAdd(&al_s[gm], s);
                    atomicAdd(&al_d[gm], d);
                }
            }
        }
    }
}

// ---------------- fused weight-compute + gather aggregation, persistent waves ----------------
// Weights recomputed inline per edge: w = exp(min(leaky(al_s[src]+al_d[dst]), 60)).
// Fixed grid of long-lived blocks; each wave strides over nodes. One node per wave
// per iteration (64 lanes x CT halfs = full row). Low-VGPR body (<=64: 8 waves/SIMD).
template <int CT, int H>
__global__ __launch_bounds__(256, 8) void gat_aggregate_f(
                                const _Float16* __restrict__ h,
                                const float* __restrict__ al_s, const float* __restrict__ al_d,
                                const int* __restrict__ indptr, const int* __restrict__ esrc,
                                const float* __restrict__ bias,
                                _Float16* __restrict__ oh,
                                int N, int act) {
    typedef _Float16 hvec __attribute__((ext_vector_type(CT)));
    const int C_ALL = CT * 64;
    int wid  = (blockIdx.x * blockDim.x + threadIdx.x) >> 6;
    int nwav = (gridDim.x * blockDim.x) >> 6;
    int lane = threadIdx.x & 63;
    int head = (lane * H) >> 6;

    for (int n = wid; n < N; n += nwav) {
        float ald = al_d[n * H + head];
        float acc[CT];
#pragma unroll
        for (int k = 0; k < CT; k++) acc[k] = 0.f;
        float dsum = 0.f;

        int beg = indptr[n], end = indptr[n + 1];   // >=1 edge (self loop)
        int idx = beg;
        for (; idx + 8 <= end; idx += 8) {
            int s[8]; float av[8]; hvec v[8];
#pragma unroll
            for (int u = 0; u < 8; u++) s[u] = esrc[idx + u];
#pragma unroll
            for (int u = 0; u < 8; u++) av[u] = al_s[s[u] * H + head];
#pragma unroll
            for (int u = 0; u < 8; u++) v[u] = *(const hvec*)(h + (size_t)s[u] * C_ALL + lane * CT);
#pragma unroll
            for (int u = 0; u < 8; u++) {
                float e = av[u] + ald;
                e = e > 0.f ? e : 0.2f * e;          // leaky_relu 0.2
                e = fminf(e, 60.f);
                float w = __expf(e);
                dsum += w;
#pragma unroll
                for (int k = 0; k < CT; k++) acc[k] += w * (float)v[u][k];
            }
        }
        if (idx + 4 <= end) {
            int s[4]; float av[4]; hvec v[4];
#pragma unroll
            for (int u = 0; u < 4; u++) s[u] = esrc[idx + u];
#pragma unroll
            for (int u = 0; u < 4; u++) av[u] = al_s[s[u] * H + head];
#pragma unroll
            for (int u = 0; u < 4; u++) v[u] = *(const hvec*)(h + (size_t)s[u] * C_ALL + lane * CT);
#pragma unroll
            for (int u = 0; u < 4; u++) {
                float e = av[u] + ald;
                e = e > 0.f ? e : 0.2f * e;
                e = fminf(e, 60.f);
                float w = __expf(e);
                dsum += w;
#pragma unroll
                for (int k = 0; k < CT; k++) acc[k] += w * (float)v[u][k];
            }
            idx += 4;
        }
        for (; idx < end; idx++) {
            int s0 = esrc[idx];
            float e = al_s[s0 * H + head] + ald;
            e = e > 0.f ? e : 0.2f * e;
            e = fminf(e, 60.f);
            float w = __expf(e);
            dsum += w;
            hvec v0 = *(const hvec*)(h + (size_t)s0 * C_ALL + lane * CT);
#pragma unroll
            for (int k = 0; k < CT; k++) acc[k] += w * (float)v0[k];
        }

        float inv = 1.f / (dsum + 1e-16f);
        size_t ob = (size_t)n * C_ALL + lane * CT;
        const float* bp = bias + lane * CT;
        hvec o;
#pragma unroll
        for (int k = 0; k < CT; k++) {
            float v = acc[k] * inv + bp[k];
            if (act == 1) v = v > 0.f ? v : (__expf(v) - 1.f);   // elu
            o[k] = (_Float16)v;
        }
        __builtin_nontemporal_store(o, (hvec*)(oh + ob));
    }
}

extern "C" void kernel_launch(void* const* d_in, const int* in_sizes, int n_in,
                              void* d_out, int out_size, void* d_ws, size_t ws_size,
                              hipStream_t stream) {
    const float* x   = (const float*)d_in[0];
    const int*   ei  = (const int*)d_in[1];
    const float* W1  = (const float*)d_in[2];
    const float* as1 = (const float*)d_in[3];
    const float* ad1 = (const float*)d_in[4];
    const float* b1  = (const float*)d_in[5];
    const float* W2  = (const float*)d_in[6];
    const float* as2 = (const float*)d_in[7];
    const float* ad2 = (const float*)d_in[8];
    const float* b2  = (const float*)d_in[9];
    const float* W3  = (const float*)d_in[10];
    const float* as3 = (const float*)d_in[11];
    const float* ad3 = (const float*)d_in[12];
    const float* b3  = (const float*)d_in[13];
    const float* M1  = (const float*)d_in[14];
    const float* mb1 = (const float*)d_in[15];
    const float* M2  = (const float*)d_in[16];
    const float* mb2 = (const float*)d_in[17];
    const float* M3  = (const float*)d_in[18];
    const float* mb3 = (const float*)d_in[19];
    float* out = (float*)d_out;

    const int N = in_sizes[0] / IN_F;   // 50000
    const int E = in_sizes[1] / 2;      // 800000
    const int* src = ei;
    const int* dst = ei + E;

    char* ws = (char*)d_ws;
    auto alloc = [&](size_t bytes) { char* p = ws; ws += (bytes + 255) & ~(size_t)255; return p; };
    _Float16* H16 = (_Float16*)alloc((size_t)N * CATF * 2);  // GEMM output (pre-aggregation)
    _Float16* P16 = (_Float16*)alloc((size_t)N * CATF * 2);  // aggregate output / GEMM A
    float* al_s = (float*)alloc((size_t)N * HEADS * 4);
    float* al_d = (float*)alloc((size_t)N * HEADS * 4);
    int* cnt    = (int*)alloc((size_t)N * 4);
    int* pos    = (int*)alloc((size_t)N * 4);
    int* indptr = (int*)alloc((size_t)(N + 1) * 4);
    int* esrc   = (int*)alloc((size_t)(E + N) * 4);
    int* bsum   = (int*)alloc(256 * 4);
    auto walloc = [&](int k, int n, _Float16*& h, _Float16*& l, bool need_lo) {
        h = (_Float16*)alloc((size_t)k * n * 2);
        l = need_lo ? (_Float16*)alloc((size_t)k * n * 2) : nullptr;
    };
    _Float16 *W1h, *W1l, *W2h, *W2l, *W3h, *W3l, *M1h, *M1l, *M2h, *M2l, *M3h, *M3l;
    walloc(IN_F, CATF, W1h, W1l, false);
    walloc(CATF, CATF, W2h, W2l, false);
    walloc(CATF, OUT_F, W3h, W3l, false);
    walloc(OUT_F, 2 * HIDC, M1h, M1l, true);
    walloc(2 * HIDC, HIDC, M2h, M2l, true);
    walloc(HIDC, OUT_F, M3h, M3l, true);

    // ---- CSR build ----
    const int nb = (N + 255) / 256;   // 196
    init_counts<<<(N + 255) / 256, 256, 0, stream>>>(cnt, N);
    count_dst<<<(E + 255) / 256, 256, 0, stream>>>(dst, E, cnt);
    scan_partial<<<nb, 256, 0, stream>>>(cnt, indptr, bsum, N);
    scan_bsums<<<1, 256, 0, stream>>>(bsum, nb);
    add_carry<<<nb, 256, 0, stream>>>(indptr, pos, bsum, N, E + N);
    scatter_edges<<<(E + N + 255) / 256, 256, 0, stream>>>(src, dst, E, N, pos, esrc);

    // ---- weight conversion + transpose (one kernel) ----
    {
        WPack p;
        int off = 0;
        auto setd = [&](int i, const float* W, _Float16* h, _Float16* l, int K, int Nc) {
            p.d[i] = WDesc{W, h, l, K, Nc, off};
            off += K * Nc;
        };
        setd(0, W1, W1h, W1l, IN_F, CATF);
        setd(1, W2, W2h, W2l, CATF, CATF);
        setd(2, W3, W3h, W3l, CATF, OUT_F);
        setd(3, M1, M1h, M1l, OUT_F, 2 * HIDC);
        setd(4, M2, M2h, M2l, 2 * HIDC, HIDC);
        setd(5, M3, M3h, M3l, HIDC, OUT_F);
        p.total = off;
        conv_w_all<<<(off + 255) / 256, 256, 0, stream>>>(p);
    }

    // gemm helpers
    auto gemm_gat = [&](const _Float16* Ap, const _Float16* Bhp, _Float16* oh,
                        const float* asrc, const float* adst, int M_, int Nc, int K, int attn_mode) {
        dim3 grid(Nc / TN, (M_ + TM - 1) / TM);
        if (attn_mode == 1)
            gemm_bt<2, 1, 1><<<grid, 256, 0, stream>>>(Ap, Bhp, nullptr, nullptr, nullptr, oh,
                                                       asrc, adst, al_s, al_d, M_, Nc, K, 0);
        else
            gemm_bt<2, 1, 2><<<grid, 256, 0, stream>>>(Ap, Bhp, nullptr, nullptr, nullptr, oh,
                                                       asrc, adst, al_s, al_d, M_, Nc, K, 0);
    };
    auto gemm_mlp16 = [&](const _Float16* Ap, const _Float16* Bhp, const _Float16* Blp,
                          const float* bias, _Float16* oh, int M_, int Nc, int K, int act) {
        dim3 grid(Nc / TN, (M_ + TM - 1) / TM);
        gemm_bt<2, 2, 0><<<grid, 256, 0, stream>>>(Ap, Bhp, Blp, bias, nullptr, oh,
                                                   nullptr, nullptr, nullptr, nullptr, M_, Nc, K, act);
    };

    // persistent-wave grid for aggregation: 2048 blocks = 8192 waves = 8 blocks/CU cap
    int gagg = (N + 3) / 4;
    if (gagg > 2048) gagg = 2048;

    // ---- input conversion: x -> P16 [N,256] ----
    conv_h16<<<((long)N * IN_F / 4 + 255) / 256, 256, 0, stream>>>(x, P16, (long)N * IN_F / 4);

    // ---- GAT layer 1 ----
    gemm_gat(P16, W1h, H16, as1, ad1, N, CATF, IN_F, 1);
    gat_aggregate_f<8, HEADS><<<gagg, 256, 0, stream>>>(H16, al_s, al_d, indptr, esrc,
                                                        b1, P16, N, 1);
    // ---- GAT layer 2 ----
    gemm_gat(P16, W2h, H16, as2, ad2, N, CATF, CATF, 1);
    gat_aggregate_f<8, HEADS><<<gagg, 256, 0, stream>>>(H16, al_s, al_d, indptr, esrc,
                                                        b2, P16, N, 1);
    // ---- GAT layer 3 (1 head, C=256, atomic attn accumulation) ----
    zero2<<<(N + 255) / 256, 256, 0, stream>>>(al_s, al_d, N);
    gemm_gat(P16, W3h, H16, as3, ad3, N, OUT_F, CATF, 2);
    gat_aggregate_f<4, 1><<<gagg, 256, 0, stream>>>(H16, al_s, al_d, indptr, esrc,
                                                    b3, P16, N, 0);
    // ---- MLP ----
    _Float16* Q16 = H16;                        // [N,256] relu out
    _Float16* R16 = P16 + (size_t)N * OUT_F;    // [N,128] second-half of P16 space (unused)
    gemm_mlp16(P16, M1h, M1l, mb1, Q16, N, 2 * HIDC, OUT_F, 1);   // relu
    gemm_mlp16(Q16, M2h, M2l, mb2, R16, N, HIDC, 2 * HIDC, 1);    // relu
    {
        dim3 grid(OUT_F / TN, (N + TM - 1) / TM);
        gemm_bt<1, 2, 0><<<grid, 256, 0, stream>>>(R16, M3h, M3l, mb3, out, nullptr,
                                                   nullptr, nullptr, nullptr, nullptr,
                                                   N, OUT_F, HIDC, 0);
    }
}

// Round 4
// 847.437 us; speedup vs baseline: 1.1946x; 1.1946x over previous
//
#include <hip/hip_runtime.h>
#include <cstdint>
#include <cstddef>

#define HEADS  4
#define HIDC   128
#define CATF   512
#define IN_F   256
#define OUT_F  256

typedef _Float16 f16x8 __attribute__((ext_vector_type(8)));
typedef _Float16 f16x4 __attribute__((ext_vector_type(4)));
typedef float f32x4  __attribute__((ext_vector_type(4)));

__device__ __forceinline__ void async16(const void* g, void* l) {
    __builtin_amdgcn_global_load_lds((const __attribute__((address_space(1))) void*)g,
                                     (__attribute__((address_space(3))) void*)l, 16, 0, 0);
}

// ---------------- CSR build ----------------
__global__ void init_counts(int* cnt, int N) {
    int i = blockIdx.x * blockDim.x + threadIdx.x;
    if (i < N) cnt[i] = 1;  // self loop
}

__global__ void count_dst(const int* __restrict__ dst, int E, int* cnt) {
    int i = blockIdx.x * blockDim.x + threadIdx.x;
    if (i < E) atomicAdd(&cnt[dst[i]], 1);
}

__global__ void scan_partial(const int* __restrict__ cnt, int* excl, int* bsum, int N) {
    __shared__ int tmp[256];
    int i = blockIdx.x * 256 + threadIdx.x;
    int v = (i < N) ? cnt[i] : 0;
    tmp[threadIdx.x] = v;
    __syncthreads();
    for (int off = 1; off < 256; off <<= 1) {
        int t = ((int)threadIdx.x >= off) ? tmp[threadIdx.x - off] : 0;
        __syncthreads();
        tmp[threadIdx.x] += t;
        __syncthreads();
    }
    if (i < N) excl[i] = tmp[threadIdx.x] - v;
    if (threadIdx.x == 255) bsum[blockIdx.x] = tmp[255];
}

__global__ void scan_bsums(int* bsum, int nb) {   // single block, nb <= 256
    __shared__ int tmp[256];
    int v = ((int)threadIdx.x < nb) ? bsum[threadIdx.x] : 0;
    tmp[threadIdx.x] = v;
    __syncthreads();
    for (int off = 1; off < 256; off <<= 1) {
        int t = ((int)threadIdx.x >= off) ? tmp[threadIdx.x - off] : 0;
        __syncthreads();
        tmp[threadIdx.x] += t;
        __syncthreads();
    }
    if ((int)threadIdx.x < nb) bsum[threadIdx.x] = tmp[threadIdx.x] - v;
}

__global__ void add_carry(int* indptr, int* pos, const int* __restrict__ bsum, int N, int total) {
    int i = blockIdx.x * blockDim.x + threadIdx.x;
    if (i < N) {
        int v = indptr[i] + bsum[i >> 8];
        indptr[i] = v;
        pos[i] = v;
    }
    if (i == 0) indptr[N] = total;
}

__global__ void scatter_edges(const int* __restrict__ src, const int* __restrict__ dst,
                              int E, int N, int* pos, int* esrc) {
    int i = blockIdx.x * blockDim.x + threadIdx.x;
    int total = E + N;
    if (i >= total) return;
    int s, d;
    if (i < E) { s = src[i]; d = dst[i]; }
    else       { s = i - E;  d = s; }
    int p = atomicAdd(&pos[d], 1);
    esrc[p] = s;
}

// ---------------- fp32 -> fp16 ----------------
__global__ void conv_h16(const float* __restrict__ in, _Float16* __restrict__ out, long n4) {
    long i = (long)blockIdx.x * blockDim.x + threadIdx.x;
    if (i >= n4) return;
    float4 v = ((const float4*)in)[i];
    f16x4 o = { (_Float16)v.x, (_Float16)v.y, (_Float16)v.z, (_Float16)v.w };
    ((f16x4*)out)[i] = o;
}

// all weights: W[K,N] fp32 -> Wt_hi/Wt_lo [N,K] fp16 (transposed, hi/lo split)
struct WDesc { const float* W; _Float16* hi; _Float16* lo; int K; int N; int off; };
struct WPack { WDesc d[6]; int total; };
__global__ void conv_w_all(WPack p) {
    int idx = blockIdx.x * blockDim.x + threadIdx.x;
    if (idx >= p.total) return;
    int wi = 0;
    while (wi < 5 && idx >= p.d[wi + 1].off) wi++;
    const WDesc& w = p.d[wi];
    int li = idx - w.off;
    int n = li / w.K, k = li - n * w.K;
    float v = w.W[(size_t)k * w.N + n];
    _Float16 h = (_Float16)v;
    w.hi[(size_t)n * w.K + k] = h;
    if (w.lo) w.lo[(size_t)n * w.K + k] = (_Float16)(v - (float)h);
}

__global__ void zero2(float* a, float* b, int n) {
    int i = blockIdx.x * blockDim.x + threadIdx.x;
    if (i < n) { a[i] = 0.f; b[i] = 0.f; }
}

// ---------------- fp16 MFMA GEMM: C = A @ W^T (+ fused attention coefs) ----------------
// A [M,K] fp16; Bh/Bl [N,K] fp16 (transposed weights). NMF=1: hi only; NMF=2: hi+lo.
// MODE 1: fp32 out; MODE 2: fp16 out.
// ATTN 0: none; 1: al_s[gm*4 + n0/128] = sum_c v*asrc[gn] (col-block == head);
//      2: atomicAdd(&al_s[gm], ...) (single head spanning multiple col-blocks).
#define TM 128
#define TN 128
#define TK 32
template <int MODE, int NMF, int ATTN>
__global__ __launch_bounds__(256) void gemm_bt(
        const _Float16* __restrict__ A,
        const _Float16* __restrict__ Bh, const _Float16* __restrict__ Bl,
        const float* __restrict__ bias,
        float* __restrict__ out_f, _Float16* __restrict__ out_h16,
        const float* __restrict__ asrc, const float* __restrict__ adst,
        float* __restrict__ al_s, float* __restrict__ al_d,
        int M, int N, int K, int act) {
    __shared__ __align__(16) _Float16 sA[TM * TK], sBh[TN * TK];
    __shared__ __align__(16) _Float16 sBl[NMF == 2 ? TN * TK : 16];
    __shared__ float sred[ATTN ? TM * 4 : 4];   // [row][s/d][wn]
    int tid = threadIdx.x;
    int wave = tid >> 6, lane = tid & 63;
    int m0 = blockIdx.y * TM, n0 = blockIdx.x * TN;
    int wm = wave >> 1, wn = wave & 1;           // 2x2 waves, each 64x64
    int srow = lane >> 2;
    int skel = (lane & 3) * 8;
    int fr = lane & 15, quad = lane >> 4;

    f32x4 acc[4][4];
#pragma unroll
    for (int i = 0; i < 4; i++)
#pragma unroll
        for (int j = 0; j < 4; j++) acc[i][j] = (f32x4){0.f, 0.f, 0.f, 0.f};

    for (int k0 = 0; k0 < K; k0 += TK) {
        __syncthreads();
#pragma unroll
        for (int c = 0; c < 2; c++) {
            int chunk = wave * 2 + c;
            int r = chunk * 16 + srow;
            int gmA = m0 + r; if (gmA >= M) gmA = M - 1;
            int gnB = n0 + r;
            size_t aoff = (size_t)gmA * K + k0 + skel;
            size_t boff = (size_t)gnB * K + k0 + skel;
            int ldso = chunk * 512;              // halfs (1 KB chunks)
            async16(A + aoff, &sA[ldso]);
            async16(Bh + boff, &sBh[ldso]);
            if (NMF == 2) async16(Bl + boff, &sBl[ldso]);
        }
        __syncthreads();

        f16x8 fa[4], fbh[4], fbl[4];
#pragma unroll
        for (int i = 0; i < 4; i++) {
            int ra = (wm * 64 + i * 16 + fr) * TK + quad * 8;
            int rb = (wn * 64 + i * 16 + fr) * TK + quad * 8;
            fa[i]  = *(const f16x8*)&sA[ra];
            fbh[i] = *(const f16x8*)&sBh[rb];
            if (NMF == 2) fbl[i] = *(const f16x8*)&sBl[rb];
        }
#pragma unroll
        for (int i = 0; i < 4; i++)
#pragma unroll
            for (int j = 0; j < 4; j++) {
                if (NMF == 2)
                    acc[i][j] = __builtin_amdgcn_mfma_f32_16x16x32_f16(fa[i], fbl[j], acc[i][j], 0, 0, 0);
                acc[i][j] = __builtin_amdgcn_mfma_f32_16x16x32_f16(fa[i], fbh[j], acc[i][j], 0, 0, 0);
            }
    }

    float avs[4], avd[4];
    if (ATTN) {
#pragma unroll
        for (int j = 0; j < 4; j++) {
            int gn = n0 + wn * 64 + j * 16 + fr;
            avs[j] = asrc[gn];
            avd[j] = adst[gn];
        }
        __syncthreads();   // done with sA; sred may alias activity timing
    }

#pragma unroll
    for (int i = 0; i < 4; i++)
#pragma unroll
        for (int r = 0; r < 4; r++) {
            int gm = m0 + wm * 64 + i * 16 + quad * 4 + r;
            if (gm >= M) continue;     // uniform across the 16-lane fr group
            float ps = 0.f, pd = 0.f;
#pragma unroll
            for (int j = 0; j < 4; j++) {
                int gn = n0 + wn * 64 + j * 16 + fr;
                float v = acc[i][j][r];
                if (bias) v += bias[gn];
                if (act == 1) v = fmaxf(v, 0.f);
                size_t o = (size_t)gm * N + gn;
                if (MODE == 1) out_f[o] = v;
                else           out_h16[o] = (_Float16)v;
                if (ATTN) { ps += v * avs[j]; pd += v * avd[j]; }
            }
            if (ATTN) {
#pragma unroll
                for (int off = 1; off < 16; off <<= 1) {
                    ps += __shfl_xor(ps, off);
                    pd += __shfl_xor(pd, off);
                }
                if (fr == 0) {
                    int lrow = wm * 64 + i * 16 + quad * 4 + r;
                    sred[lrow * 4 + 0 * 2 + wn] = ps;
                    sred[lrow * 4 + 1 * 2 + wn] = pd;
                }
            }
        }

    if (ATTN) {
        __syncthreads();
        if (tid < TM) {
            int gm = m0 + tid;
            if (gm < M) {
                float s = sred[tid * 4 + 0] + sred[tid * 4 + 1];
                float d = sred[tid * 4 + 2] + sred[tid * 4 + 3];
                if (ATTN == 1) {
                    int head = n0 >> 7;
                    al_s[gm * HEADS + head] = s;
                    al_d[gm * HEADS + head] = d;
                } else {
                    atomicAdd(&al_s[gm], s);
                    atomicAdd(&al_d[gm], d);
                }
            }
        }
    }
}

// ---------------- fused weight-compute + gather aggregation, persistent waves ----------------
// Weights recomputed inline per edge: w = exp(min(leaky(al_s[src]+al_d[dst]), 60)).
// Fixed grid of long-lived blocks; each wave strides over nodes (one node per wave
// per iteration; 64 lanes x CT halfs = full row). NO min-waves launch_bounds clause:
// R3 showed forcing 8 waves/EU caps VGPRs at 32 -> scratch spill (+180 MB sym traffic).
// Natural allocation (~44 VGPR) still permits 8 waves/SIMD.
template <int CT, int H>
__global__ __launch_bounds__(256) void gat_aggregate_f(
                                const _Float16* __restrict__ h,
                                const float* __restrict__ al_s, const float* __restrict__ al_d,
                                const int* __restrict__ indptr, const int* __restrict__ esrc,
                                const float* __restrict__ bias,
                                _Float16* __restrict__ oh,
                                int N, int act) {
    typedef _Float16 hvec __attribute__((ext_vector_type(CT)));
    const int C_ALL = CT * 64;
    int wid  = (blockIdx.x * blockDim.x + threadIdx.x) >> 6;
    int nwav = (gridDim.x * blockDim.x) >> 6;
    int lane = threadIdx.x & 63;
    int head = (lane * H) >> 6;

    for (int n = wid; n < N; n += nwav) {
        float ald = al_d[n * H + head];
        float acc[CT];
#pragma unroll
        for (int k = 0; k < CT; k++) acc[k] = 0.f;
        float dsum = 0.f;

        int beg = indptr[n], end = indptr[n + 1];   // >=1 edge (self loop)
        int idx = beg;
        for (; idx + 8 <= end; idx += 8) {
            int s[8]; float av[8]; hvec v[8];
#pragma unroll
            for (int u = 0; u < 8; u++) s[u] = esrc[idx + u];
#pragma unroll
            for (int u = 0; u < 8; u++) av[u] = al_s[s[u] * H + head];
#pragma unroll
            for (int u = 0; u < 8; u++) v[u] = *(const hvec*)(h + (size_t)s[u] * C_ALL + lane * CT);
#pragma unroll
            for (int u = 0; u < 8; u++) {
                float e = av[u] + ald;
                e = e > 0.f ? e : 0.2f * e;          // leaky_relu 0.2
                e = fminf(e, 60.f);
                float w = __expf(e);
                dsum += w;
#pragma unroll
                for (int k = 0; k < CT; k++) acc[k] += w * (float)v[u][k];
            }
        }
        if (idx + 4 <= end) {
            int s[4]; float av[4]; hvec v[4];
#pragma unroll
            for (int u = 0; u < 4; u++) s[u] = esrc[idx + u];
#pragma unroll
            for (int u = 0; u < 4; u++) av[u] = al_s[s[u] * H + head];
#pragma unroll
            for (int u = 0; u < 4; u++) v[u] = *(const hvec*)(h + (size_t)s[u] * C_ALL + lane * CT);
#pragma unroll
            for (int u = 0; u < 4; u++) {
                float e = av[u] + ald;
                e = e > 0.f ? e : 0.2f * e;
                e = fminf(e, 60.f);
                float w = __expf(e);
                dsum += w;
#pragma unroll
                for (int k = 0; k < CT; k++) acc[k] += w * (float)v[u][k];
            }
            idx += 4;
        }
        for (; idx < end; idx++) {
            int s0 = esrc[idx];
            float e = al_s[s0 * H + head] + ald;
            e = e > 0.f ? e : 0.2f * e;
            e = fminf(e, 60.f);
            float w = __expf(e);
            dsum += w;
            hvec v0 = *(const hvec*)(h + (size_t)s0 * C_ALL + lane * CT);
#pragma unroll
            for (int k = 0; k < CT; k++) acc[k] += w * (float)v0[k];
        }

        float inv = 1.f / (dsum + 1e-16f);
        size_t ob = (size_t)n * C_ALL + lane * CT;
        const float* bp = bias + lane * CT;
        hvec o;
#pragma unroll
        for (int k = 0; k < CT; k++) {
            float v = acc[k] * inv + bp[k];
            if (act == 1) v = v > 0.f ? v : (__expf(v) - 1.f);   // elu
            o[k] = (_Float16)v;
        }
        __builtin_nontemporal_store(o, (hvec*)(oh + ob));
    }
}

extern "C" void kernel_launch(void* const* d_in, const int* in_sizes, int n_in,
                              void* d_out, int out_size, void* d_ws, size_t ws_size,
                              hipStream_t stream) {
    const float* x   = (const float*)d_in[0];
    const int*   ei  = (const int*)d_in[1];
    const float* W1  = (const float*)d_in[2];
    const float* as1 = (const float*)d_in[3];
    const float* ad1 = (const float*)d_in[4];
    const float* b1  = (const float*)d_in[5];
    const float* W2  = (const float*)d_in[6];
    const float* as2 = (const float*)d_in[7];
    const float* ad2 = (const float*)d_in[8];
    const float* b2  = (const float*)d_in[9];
    const float* W3  = (const float*)d_in[10];
    const float* as3 = (const float*)d_in[11];
    const float* ad3 = (const float*)d_in[12];
    const float* b3  = (const float*)d_in[13];
    const float* M1  = (const float*)d_in[14];
    const float* mb1 = (const float*)d_in[15];
    const float* M2  = (const float*)d_in[16];
    const float* mb2 = (const float*)d_in[17];
    const float* M3  = (const float*)d_in[18];
    const float* mb3 = (const float*)d_in[19];
    float* out = (float*)d_out;

    const int N = in_sizes[0] / IN_F;   // 50000
    const int E = in_sizes[1] / 2;      // 800000
    const int* src = ei;
    const int* dst = ei + E;

    char* ws = (char*)d_ws;
    auto alloc = [&](size_t bytes) { char* p = ws; ws += (bytes + 255) & ~(size_t)255; return p; };
    _Float16* H16 = (_Float16*)alloc((size_t)N * CATF * 2);  // GEMM output (pre-aggregation)
    _Float16* P16 = (_Float16*)alloc((size_t)N * CATF * 2);  // aggregate output / GEMM A
    float* al_s = (float*)alloc((size_t)N * HEADS * 4);
    float* al_d = (float*)alloc((size_t)N * HEADS * 4);
    int* cnt    = (int*)alloc((size_t)N * 4);
    int* pos    = (int*)alloc((size_t)N * 4);
    int* indptr = (int*)alloc((size_t)(N + 1) * 4);
    int* esrc   = (int*)alloc((size_t)(E + N) * 4);
    int* bsum   = (int*)alloc(256 * 4);
    auto walloc = [&](int k, int n, _Float16*& h, _Float16*& l, bool need_lo) {
        h = (_Float16*)alloc((size_t)k * n * 2);
        l = need_lo ? (_Float16*)alloc((size_t)k * n * 2) : nullptr;
    };
    _Float16 *W1h, *W1l, *W2h, *W2l, *W3h, *W3l, *M1h, *M1l, *M2h, *M2l, *M3h, *M3l;
    walloc(IN_F, CATF, W1h, W1l, false);
    walloc(CATF, CATF, W2h, W2l, false);
    walloc(CATF, OUT_F, W3h, W3l, false);
    walloc(OUT_F, 2 * HIDC, M1h, M1l, true);
    walloc(2 * HIDC, HIDC, M2h, M2l, true);
    walloc(HIDC, OUT_F, M3h, M3l, true);

    // ---- CSR build ----
    const int nb = (N + 255) / 256;   // 196
    init_counts<<<(N + 255) / 256, 256, 0, stream>>>(cnt, N);
    count_dst<<<(E + 255) / 256, 256, 0, stream>>>(dst, E, cnt);
    scan_partial<<<nb, 256, 0, stream>>>(cnt, indptr, bsum, N);
    scan_bsums<<<1, 256, 0, stream>>>(bsum, nb);
    add_carry<<<nb, 256, 0, stream>>>(indptr, pos, bsum, N, E + N);
    scatter_edges<<<(E + N + 255) / 256, 256, 0, stream>>>(src, dst, E, N, pos, esrc);

    // ---- weight conversion + transpose (one kernel) ----
    {
        WPack p;
        int off = 0;
        auto setd = [&](int i, const float* W, _Float16* h, _Float16* l, int K, int Nc) {
            p.d[i] = WDesc{W, h, l, K, Nc, off};
            off += K * Nc;
        };
        setd(0, W1, W1h, W1l, IN_F, CATF);
        setd(1, W2, W2h, W2l, CATF, CATF);
        setd(2, W3, W3h, W3l, CATF, OUT_F);
        setd(3, M1, M1h, M1l, OUT_F, 2 * HIDC);
        setd(4, M2, M2h, M2l, 2 * HIDC, HIDC);
        setd(5, M3, M3h, M3l, HIDC, OUT_F);
        p.total = off;
        conv_w_all<<<(off + 255) / 256, 256, 0, stream>>>(p);
    }

    // gemm helpers
    auto gemm_gat = [&](const _Float16* Ap, const _Float16* Bhp, _Float16* oh,
                        const float* asrc, const float* adst, int M_, int Nc, int K, int attn_mode) {
        dim3 grid(Nc / TN, (M_ + TM - 1) / TM);
        if (attn_mode == 1)
            gemm_bt<2, 1, 1><<<grid, 256, 0, stream>>>(Ap, Bhp, nullptr, nullptr, nullptr, oh,
                                                       asrc, adst, al_s, al_d, M_, Nc, K, 0);
        else
            gemm_bt<2, 1, 2><<<grid, 256, 0, stream>>>(Ap, Bhp, nullptr, nullptr, nullptr, oh,
                                                       asrc, adst, al_s, al_d, M_, Nc, K, 0);
    };
    auto gemm_mlp16 = [&](const _Float16* Ap, const _Float16* Bhp, const _Float16* Blp,
                          const float* bias, _Float16* oh, int M_, int Nc, int K, int act) {
        dim3 grid(Nc / TN, (M_ + TM - 1) / TM);
        gemm_bt<2, 2, 0><<<grid, 256, 0, stream>>>(Ap, Bhp, Blp, bias, nullptr, oh,
                                                   nullptr, nullptr, nullptr, nullptr, M_, Nc, K, act);
    };

    // persistent-wave grid for aggregation: 2048 blocks = 8192 waves
    int gagg = (N + 3) / 4;
    if (gagg > 2048) gagg = 2048;

    // ---- input conversion: x -> P16 [N,256] ----
    conv_h16<<<((long)N * IN_F / 4 + 255) / 256, 256, 0, stream>>>(x, P16, (long)N * IN_F / 4);

    // ---- GAT layer 1 ----
    gemm_gat(P16, W1h, H16, as1, ad1, N, CATF, IN_F, 1);
    gat_aggregate_f<8, HEADS><<<gagg, 256, 0, stream>>>(H16, al_s, al_d, indptr, esrc,
                                                        b1, P16, N, 1);
    // ---- GAT layer 2 ----
    gemm_gat(P16, W2h, H16, as2, ad2, N, CATF, CATF, 1);
    gat_aggregate_f<8, HEADS><<<gagg, 256, 0, stream>>>(H16, al_s, al_d, indptr, esrc,
                                                        b2, P16, N, 1);
    // ---- GAT layer 3 (1 head, C=256, atomic attn accumulation) ----
    zero2<<<(N + 255) / 256, 256, 0, stream>>>(al_s, al_d, N);
    gemm_gat(P16, W3h, H16, as3, ad3, N, OUT_F, CATF, 2);
    gat_aggregate_f<4, 1><<<gagg, 256, 0, stream>>>(H16, al_s, al_d, indptr, esrc,
                                                    b3, P16, N, 0);
    // ---- MLP ----
    _Float16* Q16 = H16;                        // [N,256] relu out
    _Float16* R16 = P16 + (size_t)N * OUT_F;    // [N,128] second-half of P16 space (unused)
    gemm_mlp16(P16, M1h, M1l, mb1, Q16, N, 2 * HIDC, OUT_F, 1);   // relu
    gemm_mlp16(Q16, M2h, M2l, mb2, R16, N, HIDC, 2 * HIDC, 1);    // relu
    {
        dim3 grid(OUT_F / TN, (N + TM - 1) / TM);
        gemm_bt<1, 2, 0><<<grid, 256, 0, stream>>>(R16, M3h, M3l, mb3, out, nullptr,
                                                   nullptr, nullptr, nullptr, nullptr,
                                                   N, OUT_F, HIDC, 0);
    }
}

// Round 5
// 823.431 us; speedup vs baseline: 1.2294x; 1.0292x over previous
//
#include <hip/hip_runtime.h>
#include <cstdint>
#include <cstddef>

#define HEADS  4
#define HIDC   128
#define CATF   512
#define IN_F   256
#define OUT_F  256

typedef _Float16 f16x8 __attribute__((ext_vector_type(8)));
typedef _Float16 f16x4 __attribute__((ext_vector_type(4)));
typedef float f32x4  __attribute__((ext_vector_type(4)));

__device__ __forceinline__ void async16(const void* g, void* l) {
    __builtin_amdgcn_global_load_lds((const __attribute__((address_space(1))) void*)g,
                                     (__attribute__((address_space(3))) void*)l, 16, 0, 0);
}

// ---------------- CSR build ----------------
__global__ void init_counts(int* cnt, int N) {
    int i = blockIdx.x * blockDim.x + threadIdx.x;
    if (i < N) cnt[i] = 1;  // self loop
}

__global__ void count_dst(const int* __restrict__ dst, int E, int* cnt) {
    int i = blockIdx.x * blockDim.x + threadIdx.x;
    if (i < E) atomicAdd(&cnt[dst[i]], 1);
}

__global__ void scan_partial(const int* __restrict__ cnt, int* excl, int* bsum, int N) {
    __shared__ int tmp[256];
    int i = blockIdx.x * 256 + threadIdx.x;
    int v = (i < N) ? cnt[i] : 0;
    tmp[threadIdx.x] = v;
    __syncthreads();
    for (int off = 1; off < 256; off <<= 1) {
        int t = ((int)threadIdx.x >= off) ? tmp[threadIdx.x - off] : 0;
        __syncthreads();
        tmp[threadIdx.x] += t;
        __syncthreads();
    }
    if (i < N) excl[i] = tmp[threadIdx.x] - v;
    if (threadIdx.x == 255) bsum[blockIdx.x] = tmp[255];
}

__global__ void scan_bsums(int* bsum, int nb) {   // single block, nb <= 256
    __shared__ int tmp[256];
    int v = ((int)threadIdx.x < nb) ? bsum[threadIdx.x] : 0;
    tmp[threadIdx.x] = v;
    __syncthreads();
    for (int off = 1; off < 256; off <<= 1) {
        int t = ((int)threadIdx.x >= off) ? tmp[threadIdx.x - off] : 0;
        __syncthreads();
        tmp[threadIdx.x] += t;
        __syncthreads();
    }
    if ((int)threadIdx.x < nb) bsum[threadIdx.x] = tmp[threadIdx.x] - v;
}

__global__ void add_carry(int* indptr, int* pos, const int* __restrict__ bsum, int N, int total) {
    int i = blockIdx.x * blockDim.x + threadIdx.x;
    if (i < N) {
        int v = indptr[i] + bsum[i >> 8];
        indptr[i] = v;
        pos[i] = v;
    }
    if (i == 0) indptr[N] = total;
}

__global__ void scatter_edges(const int* __restrict__ src, const int* __restrict__ dst,
                              int E, int N, int* pos, int* esrc) {
    int i = blockIdx.x * blockDim.x + threadIdx.x;
    int total = E + N;
    if (i >= total) return;
    int s, d;
    if (i < E) { s = src[i]; d = dst[i]; }
    else       { s = i - E;  d = s; }
    int p = atomicAdd(&pos[d], 1);
    esrc[p] = s;
}

// ---------------- fp32 -> fp16 ----------------
__global__ void conv_h16(const float* __restrict__ in, _Float16* __restrict__ out, long n4) {
    long i = (long)blockIdx.x * blockDim.x + threadIdx.x;
    if (i >= n4) return;
    float4 v = ((const float4*)in)[i];
    f16x4 o = { (_Float16)v.x, (_Float16)v.y, (_Float16)v.z, (_Float16)v.w };
    ((f16x4*)out)[i] = o;
}

// all weights: W[K,N] fp32 -> Wt_hi/Wt_lo [N,K] fp16 (transposed, hi/lo split)
struct WDesc { const float* W; _Float16* hi; _Float16* lo; int K; int N; int off; };
struct WPack { WDesc d[6]; int total; };
__global__ void conv_w_all(WPack p) {
    int idx = blockIdx.x * blockDim.x + threadIdx.x;
    if (idx >= p.total) return;
    int wi = 0;
    while (wi < 5 && idx >= p.d[wi + 1].off) wi++;
    const WDesc& w = p.d[wi];
    int li = idx - w.off;
    int n = li / w.K, k = li - n * w.K;
    float v = w.W[(size_t)k * w.N + n];
    _Float16 h = (_Float16)v;
    w.hi[(size_t)n * w.K + k] = h;
    if (w.lo) w.lo[(size_t)n * w.K + k] = (_Float16)(v - (float)h);
}

__global__ void zero2(float* a, float* b, int n) {
    int i = blockIdx.x * blockDim.x + threadIdx.x;
    if (i < n) { a[i] = 0.f; b[i] = 0.f; }
}

// ---------------- fp16 MFMA GEMM: C = A @ W^T (+ fused attention coefs) ----------------
// Double-buffered LDS staging (T3-lite): next K-tile's global_load_lds is issued
// BEFORE compute; raw s_barrier + counted vmcnt(4/6) keep prefetch loads in flight
// across barriers (never drain to 0 mid-loop). __syncthreads would force a full
// vmcnt(0) drain per barrier and expose the whole load latency each K-step.
#define TM 128
#define TN 128
#define TK 32
template <int MODE, int NMF, int ATTN>
__global__ __launch_bounds__(256) void gemm_bt(
        const _Float16* __restrict__ A,
        const _Float16* __restrict__ Bh, const _Float16* __restrict__ Bl,
        const float* __restrict__ bias,
        float* __restrict__ out_f, _Float16* __restrict__ out_h16,
        const float* __restrict__ asrc, const float* __restrict__ adst,
        float* __restrict__ al_s, float* __restrict__ al_d,
        int M, int N, int K, int act) {
    __shared__ __align__(16) _Float16 sA[2][TM * TK], sBh[2][TN * TK];
    __shared__ __align__(16) _Float16 sBl[NMF == 2 ? 2 * TN * TK : 16];
    __shared__ float sred[ATTN ? TM * 4 : 4];   // [row][s/d][wn]
    int tid = threadIdx.x;
    int wave = tid >> 6, lane = tid & 63;
    int m0 = blockIdx.y * TM, n0 = blockIdx.x * TN;
    int wm = wave >> 1, wn = wave & 1;           // 2x2 waves, each 64x64
    int srow = lane >> 2;
    int skel = (lane & 3) * 8;
    int fr = lane & 15, quad = lane >> 4;

    f32x4 acc[4][4];
#pragma unroll
    for (int i = 0; i < 4; i++)
#pragma unroll
        for (int j = 0; j < 4; j++) acc[i][j] = (f32x4){0.f, 0.f, 0.f, 0.f};

    auto stage = [&](int buf, int k0) {
#pragma unroll
        for (int c = 0; c < 2; c++) {
            int chunk = wave * 2 + c;
            int r = chunk * 16 + srow;
            int gmA = m0 + r; if (gmA >= M) gmA = M - 1;
            int gnB = n0 + r;
            size_t aoff = (size_t)gmA * K + k0 + skel;
            size_t boff = (size_t)gnB * K + k0 + skel;
            int ldso = chunk * 512;              // halfs (1 KB chunks)
            async16(A + aoff, &sA[buf][ldso]);
            async16(Bh + boff, &sBh[buf][ldso]);
            if (NMF == 2) async16(Bl + boff, &sBl[buf * (TN * TK) + ldso]);
        }
    };

    const int nsteps = K / TK;
    stage(0, 0);
    int cur = 0;
    for (int s = 0; s < nsteps; ++s, cur ^= 1) {
        if (s + 1 < nsteps) {
            stage(cur ^ 1, (s + 1) * TK);
            // wait for CURRENT buffer's loads (oldest); next buffer's stay in flight
            if (NMF == 2) asm volatile("s_waitcnt vmcnt(6)" ::: "memory");
            else          asm volatile("s_waitcnt vmcnt(4)" ::: "memory");
        } else {
            asm volatile("s_waitcnt vmcnt(0)" ::: "memory");
        }
        __builtin_amdgcn_s_barrier();
        __builtin_amdgcn_sched_barrier(0);

        f16x8 fa[4], fbh[4], fbl[4];
#pragma unroll
        for (int i = 0; i < 4; i++) {
            int ra = (wm * 64 + i * 16 + fr) * TK + quad * 8;
            int rb = (wn * 64 + i * 16 + fr) * TK + quad * 8;
            fa[i]  = *(const f16x8*)&sA[cur][ra];
            fbh[i] = *(const f16x8*)&sBh[cur][rb];
            if (NMF == 2) fbl[i] = *(const f16x8*)&sBl[cur * (TN * TK) + rb];
        }
#pragma unroll
        for (int i = 0; i < 4; i++)
#pragma unroll
            for (int j = 0; j < 4; j++) {
                if (NMF == 2)
                    acc[i][j] = __builtin_amdgcn_mfma_f32_16x16x32_f16(fa[i], fbl[j], acc[i][j], 0, 0, 0);
                acc[i][j] = __builtin_amdgcn_mfma_f32_16x16x32_f16(fa[i], fbh[j], acc[i][j], 0, 0, 0);
            }
        __builtin_amdgcn_sched_barrier(0);
        __builtin_amdgcn_s_barrier();   // all waves done reading buf cur before next stage overwrites it
    }

    float avs[4], avd[4];
    if (ATTN) {
#pragma unroll
        for (int j = 0; j < 4; j++) {
            int gn = n0 + wn * 64 + j * 16 + fr;
            avs[j] = asrc[gn];
            avd[j] = adst[gn];
        }
    }

#pragma unroll
    for (int i = 0; i < 4; i++)
#pragma unroll
        for (int r = 0; r < 4; r++) {
            int gm = m0 + wm * 64 + i * 16 + quad * 4 + r;
            if (gm >= M) continue;     // uniform across the 16-lane fr group
            float ps = 0.f, pd = 0.f;
#pragma unroll
            for (int j = 0; j < 4; j++) {
                int gn = n0 + wn * 64 + j * 16 + fr;
                float v = acc[i][j][r];
                if (bias) v += bias[gn];
                if (act == 1) v = fmaxf(v, 0.f);
                size_t o = (size_t)gm * N + gn;
                if (MODE == 1) out_f[o] = v;
                else           out_h16[o] = (_Float16)v;
                if (ATTN) { ps += v * avs[j]; pd += v * avd[j]; }
            }
            if (ATTN) {
#pragma unroll
                for (int off = 1; off < 16; off <<= 1) {
                    ps += __shfl_xor(ps, off);
                    pd += __shfl_xor(pd, off);
                }
                if (fr == 0) {
                    int lrow = wm * 64 + i * 16 + quad * 4 + r;
                    sred[lrow * 4 + 0 * 2 + wn] = ps;
                    sred[lrow * 4 + 1 * 2 + wn] = pd;
                }
            }
        }

    if (ATTN) {
        __syncthreads();
        if (tid < TM) {
            int gm = m0 + tid;
            if (gm < M) {
                float s = sred[tid * 4 + 0] + sred[tid * 4 + 1];
                float d = sred[tid * 4 + 2] + sred[tid * 4 + 3];
                if (ATTN == 1) {
                    int head = n0 >> 7;
                    al_s[gm * HEADS + head] = s;
                    al_d[gm * HEADS + head] = d;
                } else {
                    atomicAdd(&al_s[gm], s);
                    atomicAdd(&al_d[gm], d);
                }
            }
        }
    }
}

// ---------------- fused weight-compute + gather aggregation (R1 config: best measured) ----------------
// Weights recomputed inline per edge: w = exp(min(leaky(al_s[src]+al_d[dst]), 60)).
// One node per wave, short blocks (dynamic dispatch balances degree variance).
// 44 VGPR: no launch_bounds min-clause (R3: forcing 8 w/EU -> 32 VGPR -> spill).
// No register pipeline (R2: VGPR 76 crossed the 64-reg occupancy cliff).
template <int CT, int H>
__global__ void gat_aggregate_f(const _Float16* __restrict__ h,
                                const float* __restrict__ al_s, const float* __restrict__ al_d,
                                const int* __restrict__ indptr, const int* __restrict__ esrc,
                                const float* __restrict__ bias,
                                _Float16* __restrict__ oh,
                                int N, int act) {
    typedef _Float16 hvec __attribute__((ext_vector_type(CT)));
    const int C_ALL = CT * 64;
    int n = (blockIdx.x * blockDim.x + threadIdx.x) >> 6;
    int lane = threadIdx.x & 63;
    if (n >= N) return;
    int head = (lane * H) >> 6;
    float ald = al_d[n * H + head];
    float acc[CT];
#pragma unroll
    for (int k = 0; k < CT; k++) acc[k] = 0.f;
    float dsum = 0.f;

    int beg = indptr[n], end = indptr[n + 1];   // >=1 edge (self loop)
    int idx = beg;
    for (; idx + 8 <= end; idx += 8) {
        int s[8]; float av[8]; hvec v[8];
#pragma unroll
        for (int u = 0; u < 8; u++) s[u] = esrc[idx + u];
#pragma unroll
        for (int u = 0; u < 8; u++) av[u] = al_s[s[u] * H + head];
#pragma unroll
        for (int u = 0; u < 8; u++) v[u] = *(const hvec*)(h + (size_t)s[u] * C_ALL + lane * CT);
#pragma unroll
        for (int u = 0; u < 8; u++) {
            float e = av[u] + ald;
            e = e > 0.f ? e : 0.2f * e;          // leaky_relu 0.2
            e = fminf(e, 60.f);
            float w = __expf(e);
            dsum += w;
#pragma unroll
            for (int k = 0; k < CT; k++) acc[k] += w * (float)v[u][k];
        }
    }
    if (idx + 4 <= end) {
        int s[4]; float av[4]; hvec v[4];
#pragma unroll
        for (int u = 0; u < 4; u++) s[u] = esrc[idx + u];
#pragma unroll
        for (int u = 0; u < 4; u++) av[u] = al_s[s[u] * H + head];
#pragma unroll
        for (int u = 0; u < 4; u++) v[u] = *(const hvec*)(h + (size_t)s[u] * C_ALL + lane * CT);
#pragma unroll
        for (int u = 0; u < 4; u++) {
            float e = av[u] + ald;
            e = e > 0.f ? e : 0.2f * e;
            e = fminf(e, 60.f);
            float w = __expf(e);
            dsum += w;
#pragma unroll
            for (int k = 0; k < CT; k++) acc[k] += w * (float)v[u][k];
        }
        idx += 4;
    }
    for (; idx < end; idx++) {
        int s0 = esrc[idx];
        float e = al_s[s0 * H + head] + ald;
        e = e > 0.f ? e : 0.2f * e;
        e = fminf(e, 60.f);
        float w = __expf(e);
        dsum += w;
        hvec v0 = *(const hvec*)(h + (size_t)s0 * C_ALL + lane * CT);
#pragma unroll
        for (int k = 0; k < CT; k++) acc[k] += w * (float)v0[k];
    }

    float inv = 1.f / (dsum + 1e-16f);
    size_t ob = (size_t)n * C_ALL + lane * CT;
    const float* bp = bias + lane * CT;
    hvec o;
#pragma unroll
    for (int k = 0; k < CT; k++) {
        float v = acc[k] * inv + bp[k];
        if (act == 1) v = v > 0.f ? v : (__expf(v) - 1.f);   // elu
        o[k] = (_Float16)v;
    }
    __builtin_nontemporal_store(o, (hvec*)(oh + ob));
}

extern "C" void kernel_launch(void* const* d_in, const int* in_sizes, int n_in,
                              void* d_out, int out_size, void* d_ws, size_t ws_size,
                              hipStream_t stream) {
    const float* x   = (const float*)d_in[0];
    const int*   ei  = (const int*)d_in[1];
    const float* W1  = (const float*)d_in[2];
    const float* as1 = (const float*)d_in[3];
    const float* ad1 = (const float*)d_in[4];
    const float* b1  = (const float*)d_in[5];
    const float* W2  = (const float*)d_in[6];
    const float* as2 = (const float*)d_in[7];
    const float* ad2 = (const float*)d_in[8];
    const float* b2  = (const float*)d_in[9];
    const float* W3  = (const float*)d_in[10];
    const float* as3 = (const float*)d_in[11];
    const float* ad3 = (const float*)d_in[12];
    const float* b3  = (const float*)d_in[13];
    const float* M1  = (const float*)d_in[14];
    const float* mb1 = (const float*)d_in[15];
    const float* M2  = (const float*)d_in[16];
    const float* mb2 = (const float*)d_in[17];
    const float* M3  = (const float*)d_in[18];
    const float* mb3 = (const float*)d_in[19];
    float* out = (float*)d_out;

    const int N = in_sizes[0] / IN_F;   // 50000
    const int E = in_sizes[1] / 2;      // 800000
    const int* src = ei;
    const int* dst = ei + E;

    char* ws = (char*)d_ws;
    auto alloc = [&](size_t bytes) { char* p = ws; ws += (bytes + 255) & ~(size_t)255; return p; };
    _Float16* H16 = (_Float16*)alloc((size_t)N * CATF * 2);  // GEMM output (pre-aggregation)
    _Float16* P16 = (_Float16*)alloc((size_t)N * CATF * 2);  // aggregate output / GEMM A
    float* al_s = (float*)alloc((size_t)N * HEADS * 4);
    float* al_d = (float*)alloc((size_t)N * HEADS * 4);
    int* cnt    = (int*)alloc((size_t)N * 4);
    int* pos    = (int*)alloc((size_t)N * 4);
    int* indptr = (int*)alloc((size_t)(N + 1) * 4);
    int* esrc   = (int*)alloc((size_t)(E + N) * 4);
    int* bsum   = (int*)alloc(256 * 4);
    auto walloc = [&](int k, int n, _Float16*& h, _Float16*& l, bool need_lo) {
        h = (_Float16*)alloc((size_t)k * n * 2);
        l = need_lo ? (_Float16*)alloc((size_t)k * n * 2) : nullptr;
    };
    _Float16 *W1h, *W1l, *W2h, *W2l, *W3h, *W3l, *M1h, *M1l, *M2h, *M2l, *M3h, *M3l;
    walloc(IN_F, CATF, W1h, W1l, false);
    walloc(CATF, CATF, W2h, W2l, false);
    walloc(CATF, OUT_F, W3h, W3l, false);
    walloc(OUT_F, 2 * HIDC, M1h, M1l, true);
    walloc(2 * HIDC, HIDC, M2h, M2l, true);
    walloc(HIDC, OUT_F, M3h, M3l, true);

    // ---- CSR build ----
    const int nb = (N + 255) / 256;   // 196
    init_counts<<<(N + 255) / 256, 256, 0, stream>>>(cnt, N);
    count_dst<<<(E + 255) / 256, 256, 0, stream>>>(dst, E, cnt);
    scan_partial<<<nb, 256, 0, stream>>>(cnt, indptr, bsum, N);
    scan_bsums<<<1, 256, 0, stream>>>(bsum, nb);
    add_carry<<<nb, 256, 0, stream>>>(indptr, pos, bsum, N, E + N);
    scatter_edges<<<(E + N + 255) / 256, 256, 0, stream>>>(src, dst, E, N, pos, esrc);

    // ---- weight conversion + transpose (one kernel) ----
    {
        WPack p;
        int off = 0;
        auto setd = [&](int i, const float* W, _Float16* h, _Float16* l, int K, int Nc) {
            p.d[i] = WDesc{W, h, l, K, Nc, off};
            off += K * Nc;
        };
        setd(0, W1, W1h, W1l, IN_F, CATF);
        setd(1, W2, W2h, W2l, CATF, CATF);
        setd(2, W3, W3h, W3l, CATF, OUT_F);
        setd(3, M1, M1h, M1l, OUT_F, 2 * HIDC);
        setd(4, M2, M2h, M2l, 2 * HIDC, HIDC);
        setd(5, M3, M3h, M3l, HIDC, OUT_F);
        p.total = off;
        conv_w_all<<<(off + 255) / 256, 256, 0, stream>>>(p);
    }

    // gemm helpers
    auto gemm_gat = [&](const _Float16* Ap, const _Float16* Bhp, _Float16* oh,
                        const float* asrc, const float* adst, int M_, int Nc, int K, int attn_mode) {
        dim3 grid(Nc / TN, (M_ + TM - 1) / TM);
        if (attn_mode == 1)
            gemm_bt<2, 1, 1><<<grid, 256, 0, stream>>>(Ap, Bhp, nullptr, nullptr, nullptr, oh,
                                                       asrc, adst, al_s, al_d, M_, Nc, K, 0);
        else
            gemm_bt<2, 1, 2><<<grid, 256, 0, stream>>>(Ap, Bhp, nullptr, nullptr, nullptr, oh,
                                                       asrc, adst, al_s, al_d, M_, Nc, K, 0);
    };
    auto gemm_mlp16 = [&](const _Float16* Ap, const _Float16* Bhp, const _Float16* Blp,
                          const float* bias, _Float16* oh, int M_, int Nc, int K, int act) {
        dim3 grid(Nc / TN, (M_ + TM - 1) / TM);
        gemm_bt<2, 2, 0><<<grid, 256, 0, stream>>>(Ap, Bhp, Blp, bias, nullptr, oh,
                                                   nullptr, nullptr, nullptr, nullptr, M_, Nc, K, act);
    };

    const int gwav = (N + 3) / 4;   // blocks of 4 waves, one wave per node

    // ---- input conversion: x -> P16 [N,256] ----
    conv_h16<<<((long)N * IN_F / 4 + 255) / 256, 256, 0, stream>>>(x, P16, (long)N * IN_F / 4);

    // ---- GAT layer 1 ----
    gemm_gat(P16, W1h, H16, as1, ad1, N, CATF, IN_F, 1);
    gat_aggregate_f<8, HEADS><<<gwav, 256, 0, stream>>>(H16, al_s, al_d, indptr, esrc,
                                                        b1, P16, N, 1);
    // ---- GAT layer 2 ----
    gemm_gat(P16, W2h, H16, as2, ad2, N, CATF, CATF, 1);
    gat_aggregate_f<8, HEADS><<<gwav, 256, 0, stream>>>(H16, al_s, al_d, indptr, esrc,
                                                        b2, P16, N, 1);
    // ---- GAT layer 3 (1 head, C=256, atomic attn accumulation) ----
    zero2<<<(N + 255) / 256, 256, 0, stream>>>(al_s, al_d, N);
    gemm_gat(P16, W3h, H16, as3, ad3, N, OUT_F, CATF, 2);
    gat_aggregate_f<4, 1><<<gwav, 256, 0, stream>>>(H16, al_s, al_d, indptr, esrc,
                                                    b3, P16, N, 0);
    // ---- MLP ----
    _Float16* Q16 = H16;                        // [N,256] relu out
    _Float16* R16 = P16 + (size_t)N * OUT_F;    // [N,128] second-half of P16 space (unused)
    gemm_mlp16(P16, M1h, M1l, mb1, Q16, N, 2 * HIDC, OUT_F, 1);   // relu
    gemm_mlp16(Q16, M2h, M2l, mb2, R16, N, HIDC, 2 * HIDC, 1);    // relu
    {
        dim3 grid(OUT_F / TN, (N + TM - 1) / TM);
        gemm_bt<1, 2, 0><<<grid, 256, 0, stream>>>(R16, M3h, M3l, mb3, out, nullptr,
                                                   nullptr, nullptr, nullptr, nullptr,
                                                   N, OUT_F, HIDC, 0);
    }
}

// Round 6
// 736.314 us; speedup vs baseline: 1.3749x; 1.1183x over previous
//
#include <hip/hip_runtime.h>
#include <cstdint>
#include <cstddef>

#define HEADS  4
#define HIDC   128
#define CATF   512
#define IN_F   256
#define OUT_F  256

typedef _Float16 f16x8 __attribute__((ext_vector_type(8)));
typedef _Float16 f16x4 __attribute__((ext_vector_type(4)));
typedef float f32x4  __attribute__((ext_vector_type(4)));

__device__ __forceinline__ void async16(const void* g, void* l) {
    __builtin_amdgcn_global_load_lds((const __attribute__((address_space(1))) void*)g,
                                     (__attribute__((address_space(3))) void*)l, 16, 0, 0);
}

// ---------------- CSR build ----------------
__global__ void init_counts(int* cnt, int N) {
    int i = blockIdx.x * blockDim.x + threadIdx.x;
    if (i < N) cnt[i] = 1;  // self loop
}

__global__ void count_dst(const int* __restrict__ dst, int E, int* cnt) {
    int i = blockIdx.x * blockDim.x + threadIdx.x;
    if (i < E) atomicAdd(&cnt[dst[i]], 1);
}

__global__ void scan_partial(const int* __restrict__ cnt, int* excl, int* bsum, int N) {
    __shared__ int tmp[256];
    int i = blockIdx.x * 256 + threadIdx.x;
    int v = (i < N) ? cnt[i] : 0;
    tmp[threadIdx.x] = v;
    __syncthreads();
    for (int off = 1; off < 256; off <<= 1) {
        int t = ((int)threadIdx.x >= off) ? tmp[threadIdx.x - off] : 0;
        __syncthreads();
        tmp[threadIdx.x] += t;
        __syncthreads();
    }
    if (i < N) excl[i] = tmp[threadIdx.x] - v;
    if (threadIdx.x == 255) bsum[blockIdx.x] = tmp[255];
}

__global__ void scan_bsums(int* bsum, int nb) {   // single block, nb <= 256
    __shared__ int tmp[256];
    int v = ((int)threadIdx.x < nb) ? bsum[threadIdx.x] : 0;
    tmp[threadIdx.x] = v;
    __syncthreads();
    for (int off = 1; off < 256; off <<= 1) {
        int t = ((int)threadIdx.x >= off) ? tmp[threadIdx.x - off] : 0;
        __syncthreads();
        tmp[threadIdx.x] += t;
        __syncthreads();
    }
    if ((int)threadIdx.x < nb) bsum[threadIdx.x] = tmp[threadIdx.x] - v;
}

__global__ void add_carry(int* indptr, int* pos, const int* __restrict__ bsum, int N, int total) {
    int i = blockIdx.x * blockDim.x + threadIdx.x;
    if (i < N) {
        int v = indptr[i] + bsum[i >> 8];
        indptr[i] = v;
        pos[i] = v;
    }
    if (i == 0) indptr[N] = total;
}

__global__ void scatter_edges(const int* __restrict__ src, const int* __restrict__ dst,
                              int E, int N, int* pos, int* esrc) {
    int i = blockIdx.x * blockDim.x + threadIdx.x;
    int total = E + N;
    if (i >= total) return;
    int s, d;
    if (i < E) { s = src[i]; d = dst[i]; }
    else       { s = i - E;  d = s; }
    int p = atomicAdd(&pos[d], 1);
    esrc[p] = s;
}

// ---------------- fp32 -> fp16 ----------------
__global__ void conv_h16(const float* __restrict__ in, _Float16* __restrict__ out, long n4) {
    long i = (long)blockIdx.x * blockDim.x + threadIdx.x;
    if (i >= n4) return;
    float4 v = ((const float4*)in)[i];
    f16x4 o = { (_Float16)v.x, (_Float16)v.y, (_Float16)v.z, (_Float16)v.w };
    ((f16x4*)out)[i] = o;
}

// all weights: W[K,N] fp32 -> Wt_hi/Wt_lo [N,K] fp16 (transposed, hi/lo split)
struct WDesc { const float* W; _Float16* hi; _Float16* lo; int K; int N; int off; };
struct WPack { WDesc d[6]; int total; };
__global__ void conv_w_all(WPack p) {
    int idx = blockIdx.x * blockDim.x + threadIdx.x;
    if (idx >= p.total) return;
    int wi = 0;
    while (wi < 5 && idx >= p.d[wi + 1].off) wi++;
    const WDesc& w = p.d[wi];
    int li = idx - w.off;
    int n = li / w.K, k = li - n * w.K;
    float v = w.W[(size_t)k * w.N + n];
    _Float16 h = (_Float16)v;
    w.hi[(size_t)n * w.K + k] = h;
    if (w.lo) w.lo[(size_t)n * w.K + k] = (_Float16)(v - (float)h);
}

__global__ void zero2(float* a, float* b, int n) {
    int i = blockIdx.x * blockDim.x + threadIdx.x;
    if (i < n) { a[i] = 0.f; b[i] = 0.f; }
}

// ---------------- fp16 MFMA GEMM: C = A @ W^T (+ fused attention coefs) ----------------
// Double-buffered LDS staging with counted vmcnt (R5). New this round:
//  * XCD-chunked bijective block swizzle (m204): the N-blocks sharing an A-panel
//    become XCD-contiguous -> A fetched once per panel instead of 4x.
//  * MODE2 epilogue: C restaged through LDS (aliases the dead staging buffers,
//    16B-block XOR swizzle keeps ds_writes ~conflict-free) then 8x coalesced
//    16-B global stores per thread, replacing 64 scalar 2B stores + size_t muls.
#define TM 128
#define TN 128
#define TK 32
template <int MODE, int NMF, int ATTN>
__global__ __launch_bounds__(256) void gemm_bt(
        const _Float16* __restrict__ A,
        const _Float16* __restrict__ Bh, const _Float16* __restrict__ Bl,
        const float* __restrict__ bias,
        float* __restrict__ out_f, _Float16* __restrict__ out_h16,
        const float* __restrict__ asrc, const float* __restrict__ adst,
        float* __restrict__ al_s, float* __restrict__ al_d,
        int M, int N, int K, int act) {
    // flat LDS so the C-stage can alias the staging buffers after the K-loop
    __shared__ __align__(16) char smem[(NMF == 2 ? 49152 : 32768) + (ATTN ? 2048 : 16)];
    _Float16* sA  = (_Float16*)smem;              // [2][TM*TK]
    _Float16* sBh = (_Float16*)(smem + 16384);    // [2][TN*TK]
    _Float16* sBl = (_Float16*)(smem + 32768);    // [2][TN*TK] (NMF==2 only)
    float* sred   = (float*)(smem + (NMF == 2 ? 49152 : 32768));   // [TM][4]

    int tid = threadIdx.x;
    int wave = tid >> 6, lane = tid & 63;
    // XCD-chunked bijective swizzle (nwg need not divide 8)
    int nwg = gridDim.x * gridDim.y;
    int id  = blockIdx.y * gridDim.x + blockIdx.x;
    int qq = nwg >> 3, rr = nwg & 7;
    int xcd = id & 7, li = id >> 3;
    int wg = (xcd < rr ? xcd * (qq + 1) : rr * (qq + 1) + (xcd - rr) * qq) + li;
    int by = wg / (int)gridDim.x;
    int bx = wg - by * (int)gridDim.x;
    int m0 = by * TM, n0 = bx * TN;
    int wm = wave >> 1, wn = wave & 1;           // 2x2 waves, each 64x64
    int srow = lane >> 2;
    int skel = (lane & 3) * 8;
    int fr = lane & 15, quad = lane >> 4;

    f32x4 acc[4][4];
#pragma unroll
    for (int i = 0; i < 4; i++)
#pragma unroll
        for (int j = 0; j < 4; j++) acc[i][j] = (f32x4){0.f, 0.f, 0.f, 0.f};

    auto stage = [&](int buf, int k0) {
#pragma unroll
        for (int c = 0; c < 2; c++) {
            int chunk = wave * 2 + c;
            int r = chunk * 16 + srow;
            int gmA = m0 + r; if (gmA >= M) gmA = M - 1;
            int gnB = n0 + r;
            size_t aoff = (size_t)gmA * K + k0 + skel;
            size_t boff = (size_t)gnB * K + k0 + skel;
            int ldso = buf * (TM * TK) + chunk * 512;    // halfs (1 KB chunks)
            async16(A + aoff, &sA[ldso]);
            async16(Bh + boff, &sBh[ldso]);
            if (NMF == 2) async16(Bl + boff, &sBl[ldso]);
        }
    };

    const int nsteps = K / TK;
    stage(0, 0);
    int cur = 0;
    for (int s = 0; s < nsteps; ++s, cur ^= 1) {
        if (s + 1 < nsteps) {
            stage(cur ^ 1, (s + 1) * TK);
            // wait for CURRENT buffer's loads (oldest); next buffer's stay in flight
            if (NMF == 2) asm volatile("s_waitcnt vmcnt(6)" ::: "memory");
            else          asm volatile("s_waitcnt vmcnt(4)" ::: "memory");
        } else {
            asm volatile("s_waitcnt vmcnt(0)" ::: "memory");
        }
        __builtin_amdgcn_s_barrier();
        __builtin_amdgcn_sched_barrier(0);

        f16x8 fa[4], fbh[4], fbl[4];
#pragma unroll
        for (int i = 0; i < 4; i++) {
            int ra = cur * (TM * TK) + (wm * 64 + i * 16 + fr) * TK + quad * 8;
            int rb = cur * (TN * TK) + (wn * 64 + i * 16 + fr) * TK + quad * 8;
            fa[i]  = *(const f16x8*)&sA[ra];
            fbh[i] = *(const f16x8*)&sBh[rb];
            if (NMF == 2) fbl[i] = *(const f16x8*)&sBl[rb];
        }
#pragma unroll
        for (int i = 0; i < 4; i++)
#pragma unroll
            for (int j = 0; j < 4; j++) {
                if (NMF == 2)
                    acc[i][j] = __builtin_amdgcn_mfma_f32_16x16x32_f16(fa[i], fbl[j], acc[i][j], 0, 0, 0);
                acc[i][j] = __builtin_amdgcn_mfma_f32_16x16x32_f16(fa[i], fbh[j], acc[i][j], 0, 0, 0);
            }
        __builtin_amdgcn_sched_barrier(0);
        __builtin_amdgcn_s_barrier();   // all waves done reading buf cur before next stage overwrites it
    }

    // ---- epilogue ----
    float avs[4], avd[4], bv[4];
#pragma unroll
    for (int j = 0; j < 4; j++) {
        int gn = n0 + wn * 64 + j * 16 + fr;
        if (ATTN) { avs[j] = asrc[gn]; avd[j] = adst[gn]; }
        bv[j] = bias ? bias[gn] : 0.f;
    }

    if (ATTN) {
#pragma unroll
        for (int i = 0; i < 4; i++)
#pragma unroll
            for (int r = 0; r < 4; r++) {
                float ps = 0.f, pd = 0.f;
#pragma unroll
                for (int j = 0; j < 4; j++) {
                    float v = acc[i][j][r];
                    ps += v * avs[j]; pd += v * avd[j];
                }
#pragma unroll
                for (int off = 1; off < 16; off <<= 1) {
                    ps += __shfl_xor(ps, off);
                    pd += __shfl_xor(pd, off);
                }
                if (fr == 0) {
                    int lrow = wm * 64 + i * 16 + quad * 4 + r;
                    sred[lrow * 4 + 0 * 2 + wn] = ps;
                    sred[lrow * 4 + 1 * 2 + wn] = pd;
                }
            }
    }

    if (MODE == 1) {
        // scalar fp32 store path (final GEMM only; no ATTN at call sites)
#pragma unroll
        for (int i = 0; i < 4; i++)
#pragma unroll
            for (int r = 0; r < 4; r++) {
                int gm = m0 + wm * 64 + i * 16 + quad * 4 + r;
                if (gm >= M) continue;
#pragma unroll
                for (int j = 0; j < 4; j++) {
                    int gn = n0 + wn * 64 + j * 16 + fr;
                    float v = acc[i][j][r] + bv[j];
                    if (act == 1) v = fmaxf(v, 0.f);
                    out_f[(size_t)gm * N + gn] = v;
                }
            }
        __syncthreads();
    } else {
        // LDS-restaged, vectorized fp16 C-write. cst aliases sA/sBh (dead).
        _Float16* cst = (_Float16*)smem;             // [128][128] halfs, 16B-block XOR swizzle
#pragma unroll
        for (int i = 0; i < 4; i++) {
            int svb = ((wm * 16 + i * 4 + quad) << 1) & 15;   // ((row>>2)<<1)&15
#pragma unroll
            for (int j = 0; j < 4; j++) {
#pragma unroll
                for (int r = 0; r < 4; r++) {
                    int row = wm * 64 + i * 16 + quad * 4 + r;
                    int col = wn * 64 + j * 16 + fr;
                    float v = acc[i][j][r] + bv[j];
                    if (act == 1) v = fmaxf(v, 0.f);
                    int blk = (col >> 3) ^ svb;
                    cst[row * 128 + (blk << 3) + (col & 7)] = (_Float16)v;
                }
            }
        }
        __syncthreads();
#pragma unroll
        for (int q = 0; q < 8; q++) {
            int c = tid + 256 * q;
            int row = c >> 4, b = c & 15;
            int gm = m0 + row;
            if (gm < M) {
                int svb = ((row >> 2) << 1) & 15;
                f16x8 val = *(const f16x8*)&cst[row * 128 + ((b ^ svb) << 3)];
                *(f16x8*)&out_h16[(size_t)gm * N + n0 + b * 8] = val;
            }
        }
    }

    if (ATTN) {
        // __syncthreads above makes sred visible
        if (tid < TM) {
            int gm = m0 + tid;
            if (gm < M) {
                float s = sred[tid * 4 + 0] + sred[tid * 4 + 1];
                float d = sred[tid * 4 + 2] + sred[tid * 4 + 3];
                if (ATTN == 1) {
                    int head = n0 >> 7;
                    al_s[gm * HEADS + head] = s;
                    al_d[gm * HEADS + head] = d;
                } else {
                    atomicAdd(&al_s[gm], s);
                    atomicAdd(&al_d[gm], d);
                }
            }
        }
    }
}

// ---------------- fused weight-compute + gather aggregation (R1 config: best measured) ----------------
// Weights recomputed inline per edge: w = exp(min(leaky(al_s[src]+al_d[dst]), 60)).
// One node per wave, short blocks (dynamic dispatch balances degree variance).
// 44 VGPR: no launch_bounds min-clause (R3: forcing 8 w/EU -> 32 VGPR -> spill).
// No register pipeline (R2: VGPR 76 crossed the 64-reg occupancy cliff).
template <int CT, int H>
__global__ void gat_aggregate_f(const _Float16* __restrict__ h,
                                const float* __restrict__ al_s, const float* __restrict__ al_d,
                                const int* __restrict__ indptr, const int* __restrict__ esrc,
                                const float* __restrict__ bias,
                                _Float16* __restrict__ oh,
                                int N, int act) {
    typedef _Float16 hvec __attribute__((ext_vector_type(CT)));
    const int C_ALL = CT * 64;
    int n = (blockIdx.x * blockDim.x + threadIdx.x) >> 6;
    int lane = threadIdx.x & 63;
    if (n >= N) return;
    int head = (lane * H) >> 6;
    float ald = al_d[n * H + head];
    float acc[CT];
#pragma unroll
    for (int k = 0; k < CT; k++) acc[k] = 0.f;
    float dsum = 0.f;

    int beg = indptr[n], end = indptr[n + 1];   // >=1 edge (self loop)
    int idx = beg;
    for (; idx + 8 <= end; idx += 8) {
        int s[8]; float av[8]; hvec v[8];
#pragma unroll
        for (int u = 0; u < 8; u++) s[u] = esrc[idx + u];
#pragma unroll
        for (int u = 0; u < 8; u++) av[u] = al_s[s[u] * H + head];
#pragma unroll
        for (int u = 0; u < 8; u++) v[u] = *(const hvec*)(h + (size_t)s[u] * C_ALL + lane * CT);
#pragma unroll
        for (int u = 0; u < 8; u++) {
            float e = av[u] + ald;
            e = e > 0.f ? e : 0.2f * e;          // leaky_relu 0.2
            e = fminf(e, 60.f);
            float w = __expf(e);
            dsum += w;
#pragma unroll
            for (int k = 0; k < CT; k++) acc[k] += w * (float)v[u][k];
        }
    }
    if (idx + 4 <= end) {
        int s[4]; float av[4]; hvec v[4];
#pragma unroll
        for (int u = 0; u < 4; u++) s[u] = esrc[idx + u];
#pragma unroll
        for (int u = 0; u < 4; u++) av[u] = al_s[s[u] * H + head];
#pragma unroll
        for (int u = 0; u < 4; u++) v[u] = *(const hvec*)(h + (size_t)s[u] * C_ALL + lane * CT);
#pragma unroll
        for (int u = 0; u < 4; u++) {
            float e = av[u] + ald;
            e = e > 0.f ? e : 0.2f * e;
            e = fminf(e, 60.f);
            float w = __expf(e);
            dsum += w;
#pragma unroll
            for (int k = 0; k < CT; k++) acc[k] += w * (float)v[u][k];
        }
        idx += 4;
    }
    for (; idx < end; idx++) {
        int s0 = esrc[idx];
        float e = al_s[s0 * H + head] + ald;
        e = e > 0.f ? e : 0.2f * e;
        e = fminf(e, 60.f);
        float w = __expf(e);
        dsum += w;
        hvec v0 = *(const hvec*)(h + (size_t)s0 * C_ALL + lane * CT);
#pragma unroll
        for (int k = 0; k < CT; k++) acc[k] += w * (float)v0[k];
    }

    float inv = 1.f / (dsum + 1e-16f);
    size_t ob = (size_t)n * C_ALL + lane * CT;
    const float* bp = bias + lane * CT;
    hvec o;
#pragma unroll
    for (int k = 0; k < CT; k++) {
        float v = acc[k] * inv + bp[k];
        if (act == 1) v = v > 0.f ? v : (__expf(v) - 1.f);   // elu
        o[k] = (_Float16)v;
    }
    __builtin_nontemporal_store(o, (hvec*)(oh + ob));
}

extern "C" void kernel_launch(void* const* d_in, const int* in_sizes, int n_in,
                              void* d_out, int out_size, void* d_ws, size_t ws_size,
                              hipStream_t stream) {
    const float* x   = (const float*)d_in[0];
    const int*   ei  = (const int*)d_in[1];
    const float* W1  = (const float*)d_in[2];
    const float* as1 = (const float*)d_in[3];
    const float* ad1 = (const float*)d_in[4];
    const float* b1  = (const float*)d_in[5];
    const float* W2  = (const float*)d_in[6];
    const float* as2 = (const float*)d_in[7];
    const float* ad2 = (const float*)d_in[8];
    const float* b2  = (const float*)d_in[9];
    const float* W3  = (const float*)d_in[10];
    const float* as3 = (const float*)d_in[11];
    const float* ad3 = (const float*)d_in[12];
    const float* b3  = (const float*)d_in[13];
    const float* M1  = (const float*)d_in[14];
    const float* mb1 = (const float*)d_in[15];
    const float* M2  = (const float*)d_in[16];
    const float* mb2 = (const float*)d_in[17];
    const float* M3  = (const float*)d_in[18];
    const float* mb3 = (const float*)d_in[19];
    float* out = (float*)d_out;

    const int N = in_sizes[0] / IN_F;   // 50000
    const int E = in_sizes[1] / 2;      // 800000
    const int* src = ei;
    const int* dst = ei + E;

    char* ws = (char*)d_ws;
    auto alloc = [&](size_t bytes) { char* p = ws; ws += (bytes + 255) & ~(size_t)255; return p; };
    _Float16* H16 = (_Float16*)alloc((size_t)N * CATF * 2);  // GEMM output (pre-aggregation)
    _Float16* P16 = (_Float16*)alloc((size_t)N * CATF * 2);  // aggregate output / GEMM A
    float* al_s = (float*)alloc((size_t)N * HEADS * 4);
    float* al_d = (float*)alloc((size_t)N * HEADS * 4);
    int* cnt    = (int*)alloc((size_t)N * 4);
    int* pos    = (int*)alloc((size_t)N * 4);
    int* indptr = (int*)alloc((size_t)(N + 1) * 4);
    int* esrc   = (int*)alloc((size_t)(E + N) * 4);
    int* bsum   = (int*)alloc(256 * 4);
    auto walloc = [&](int k, int n, _Float16*& h, _Float16*& l, bool need_lo) {
        h = (_Float16*)alloc((size_t)k * n * 2);
        l = need_lo ? (_Float16*)alloc((size_t)k * n * 2) : nullptr;
    };
    _Float16 *W1h, *W1l, *W2h, *W2l, *W3h, *W3l, *M1h, *M1l, *M2h, *M2l, *M3h, *M3l;
    walloc(IN_F, CATF, W1h, W1l, false);
    walloc(CATF, CATF, W2h, W2l, false);
    walloc(CATF, OUT_F, W3h, W3l, false);
    walloc(OUT_F, 2 * HIDC, M1h, M1l, true);
    walloc(2 * HIDC, HIDC, M2h, M2l, true);
    walloc(HIDC, OUT_F, M3h, M3l, true);

    // ---- CSR build ----
    const int nb = (N + 255) / 256;   // 196
    init_counts<<<(N + 255) / 256, 256, 0, stream>>>(cnt, N);
    count_dst<<<(E + 255) / 256, 256, 0, stream>>>(dst, E, cnt);
    scan_partial<<<nb, 256, 0, stream>>>(cnt, indptr, bsum, N);
    scan_bsums<<<1, 256, 0, stream>>>(bsum, nb);
    add_carry<<<nb, 256, 0, stream>>>(indptr, pos, bsum, N, E + N);
    scatter_edges<<<(E + N + 255) / 256, 256, 0, stream>>>(src, dst, E, N, pos, esrc);

    // ---- weight conversion + transpose (one kernel) ----
    {
        WPack p;
        int off = 0;
        auto setd = [&](int i, const float* W, _Float16* h, _Float16* l, int K, int Nc) {
            p.d[i] = WDesc{W, h, l, K, Nc, off};
            off += K * Nc;
        };
        setd(0, W1, W1h, W1l, IN_F, CATF);
        setd(1, W2, W2h, W2l, CATF, CATF);
        setd(2, W3, W3h, W3l, CATF, OUT_F);
        setd(3, M1, M1h, M1l, OUT_F, 2 * HIDC);
        setd(4, M2, M2h, M2l, 2 * HIDC, HIDC);
        setd(5, M3, M3h, M3l, HIDC, OUT_F);
        p.total = off;
        conv_w_all<<<(off + 255) / 256, 256, 0, stream>>>(p);
    }

    // gemm helpers
    auto gemm_gat = [&](const _Float16* Ap, const _Float16* Bhp, _Float16* oh,
                        const float* asrc, const float* adst, int M_, int Nc, int K, int attn_mode) {
        dim3 grid(Nc / TN, (M_ + TM - 1) / TM);
        if (attn_mode == 1)
            gemm_bt<2, 1, 1><<<grid, 256, 0, stream>>>(Ap, Bhp, nullptr, nullptr, nullptr, oh,
                                                       asrc, adst, al_s, al_d, M_, Nc, K, 0);
        else
            gemm_bt<2, 1, 2><<<grid, 256, 0, stream>>>(Ap, Bhp, nullptr, nullptr, nullptr, oh,
                                                       asrc, adst, al_s, al_d, M_, Nc, K, 0);
    };
    auto gemm_mlp16 = [&](const _Float16* Ap, const _Float16* Bhp, const _Float16* Blp,
                          const float* bias, _Float16* oh, int M_, int Nc, int K, int act) {
        dim3 grid(Nc / TN, (M_ + TM - 1) / TM);
        gemm_bt<2, 2, 0><<<grid, 256, 0, stream>>>(Ap, Bhp, Blp, bias, nullptr, oh,
                                                   nullptr, nullptr, nullptr, nullptr, M_, Nc, K, act);
    };

    const int gwav = (N + 3) / 4;   // blocks of 4 waves, one wave per node

    // ---- input conversion: x -> P16 [N,256] ----
    conv_h16<<<((long)N * IN_F / 4 + 255) / 256, 256, 0, stream>>>(x, P16, (long)N * IN_F / 4);

    // ---- GAT layer 1 ----
    gemm_gat(P16, W1h, H16, as1, ad1, N, CATF, IN_F, 1);
    gat_aggregate_f<8, HEADS><<<gwav, 256, 0, stream>>>(H16, al_s, al_d, indptr, esrc,
                                                        b1, P16, N, 1);
    // ---- GAT layer 2 ----
    gemm_gat(P16, W2h, H16, as2, ad2, N, CATF, CATF, 1);
    gat_aggregate_f<8, HEADS><<<gwav, 256, 0, stream>>>(H16, al_s, al_d, indptr, esrc,
                                                        b2, P16, N, 1);
    // ---- GAT layer 3 (1 head, C=256, atomic attn accumulation) ----
    zero2<<<(N + 255) / 256, 256, 0, stream>>>(al_s, al_d, N);
    gemm_gat(P16, W3h, H16, as3, ad3, N, OUT_F, CATF, 2);
    gat_aggregate_f<4, 1><<<gwav, 256, 0, stream>>>(H16, al_s, al_d, indptr, esrc,
                                                    b3, P16, N, 0);
    // ---- MLP ----
    _Float16* Q16 = H16;                        // [N,256] relu out
    _Float16* R16 = P16 + (size_t)N * OUT_F;    // [N,128] second-half of P16 space (unused)
    gemm_mlp16(P16, M1h, M1l, mb1, Q16, N, 2 * HIDC, OUT_F, 1);   // relu
    gemm_mlp16(Q16, M2h, M2l, mb2, R16, N, HIDC, 2 * HIDC, 1);    // relu
    {
        dim3 grid(OUT_F / TN, (N + TM - 1) / TM);
        gemm_bt<1, 2, 0><<<grid, 256, 0, stream>>>(R16, M3h, M3l, mb3, out, nullptr,
                                                   nullptr, nullptr, nullptr, nullptr,
                                                   N, OUT_F, HIDC, 0);
    }
}